// Round 1
// baseline (902.856 us; speedup 1.0000x reference)
//
#include <hip/hip_runtime.h>

#define NT 64

// ---------------------------------------------------------------------------
// Kernel 1: five 64x64 GEMMs over all nodes.
//   m = blockIdx.y + m_off; m in [0,3] -> y[m] = x @ weight[m]   (to workspace)
//                           m == 4     -> out  = x @ root_w + b  (initializes out)
// Block: 256 threads, 64-node tile, full 64 output channels.
// ---------------------------------------------------------------------------
__global__ __launch_bounds__(256) void gemm5_kernel(
    const float* __restrict__ x, const float* __restrict__ weight,
    const float* __restrict__ root_w, const float* __restrict__ root_b,
    float* __restrict__ out, float* __restrict__ y, int n_nodes, int m_off)
{
    __shared__ float xs[NT][65];   // +1 pad: bank-conflict-free column reads
    __shared__ float ws[64][65];

    const int tid   = threadIdx.x;
    const int m     = blockIdx.y + m_off;
    const int node0 = blockIdx.x * NT;
    const float* __restrict__ W = (m < 4) ? (weight + m * 4096) : root_w;

    // Stage W (64x64) and x tile (64x64) via coalesced float4 loads.
    #pragma unroll
    for (int i = 0; i < 4; ++i) {
        int v  = tid + i * 256;       // float4 index 0..1023
        int r  = v >> 4;
        int cq = v & 15;
        float4 w4 = reinterpret_cast<const float4*>(W)[v];
        ws[r][cq * 4 + 0] = w4.x; ws[r][cq * 4 + 1] = w4.y;
        ws[r][cq * 4 + 2] = w4.z; ws[r][cq * 4 + 3] = w4.w;
        int node = node0 + r;
        float4 x4 = (node < n_nodes)
                        ? reinterpret_cast<const float4*>(x)[node * 16 + cq]
                        : make_float4(0.f, 0.f, 0.f, 0.f);
        xs[r][cq * 4 + 0] = x4.x; xs[r][cq * 4 + 1] = x4.y;
        xs[r][cq * 4 + 2] = x4.z; xs[r][cq * 4 + 3] = x4.w;
    }
    __syncthreads();

    // Each thread: 4 nodes x 4 cols register tile.
    const int tc = (tid & 15) * 4;   // col base
    const int tr = (tid >> 4) * 4;   // node base (within tile)

    float acc[4][4];
    #pragma unroll
    for (int i = 0; i < 4; ++i)
        #pragma unroll
        for (int j = 0; j < 4; ++j) acc[i][j] = 0.f;

    #pragma unroll 4
    for (int k = 0; k < 64; ++k) {
        float xv[4], wv[4];
        #pragma unroll
        for (int i = 0; i < 4; ++i) xv[i] = xs[tr + i][k];
        #pragma unroll
        for (int j = 0; j < 4; ++j) wv[j] = ws[k][tc + j];
        #pragma unroll
        for (int i = 0; i < 4; ++i)
            #pragma unroll
            for (int j = 0; j < 4; ++j) acc[i][j] += xv[i] * wv[j];
    }

    float bias[4] = {0.f, 0.f, 0.f, 0.f};
    if (m == 4) {
        #pragma unroll
        for (int j = 0; j < 4; ++j) bias[j] = root_b[tc + j];
    }
    float* __restrict__ dst = (m < 4) ? (y + (size_t)m * n_nodes * 64) : out;
    #pragma unroll
    for (int i = 0; i < 4; ++i) {
        int node = node0 + tr + i;
        if (node < n_nodes) {
            float4 o = make_float4(acc[i][0] + bias[0], acc[i][1] + bias[1],
                                   acc[i][2] + bias[2], acc[i][3] + bias[3]);
            reinterpret_cast<float4*>(dst)[node * 16 + (tc >> 2)] = o;
        }
    }
}

// ---------------------------------------------------------------------------
// Kernel 2: per-edge gather from y[type][src] + scatter-add to out[dst].
// 16 threads per edge; each thread: one float4 read + 4 atomicAdds.
// ---------------------------------------------------------------------------
__global__ __launch_bounds__(256) void scatter_kernel(
    const int* __restrict__ ei, const int* __restrict__ et,
    const float* __restrict__ y, float* __restrict__ out,
    int n_edges, int n_nodes)
{
    long idx = (long)blockIdx.x * blockDim.x + threadIdx.x;
    if (idx >= (long)n_edges * 16) return;
    int e  = (int)(idx >> 4);
    int cq = (int)(idx & 15);
    int src  = ei[e];
    int dstn = ei[n_edges + e];
    int t    = et[e];
    float4 v = reinterpret_cast<const float4*>(y)[((long)t * n_nodes + src) * 16 + cq];
    float* o = out + (long)dstn * 64 + cq * 4;
    atomicAdd(o + 0, v.x);
    atomicAdd(o + 1, v.y);
    atomicAdd(o + 2, v.z);
    atomicAdd(o + 3, v.w);
}

// ---------------------------------------------------------------------------
// Fallback (workspace too small): direct per-edge matmul, one wave per edge.
// lane c computes msg[c] = sum_k x[src][k] * W[t][k][c] via shfl broadcast.
// ---------------------------------------------------------------------------
__global__ __launch_bounds__(256) void edge_direct_kernel(
    const float* __restrict__ x, const int* __restrict__ ei,
    const int* __restrict__ et, const float* __restrict__ weight,
    float* __restrict__ out, int n_edges)
{
    int gwave  = (int)((blockIdx.x * (long)blockDim.x + threadIdx.x) >> 6);
    int lane   = threadIdx.x & 63;
    int nwaves = (int)(((long)gridDim.x * blockDim.x) >> 6);
    for (int e = gwave; e < n_edges; e += nwaves) {
        int src  = ei[e];
        int dstn = ei[n_edges + e];
        int t    = et[e];
        float xv = x[src * 64 + lane];
        const float* __restrict__ W = weight + t * 4096;
        float acc = 0.f;
        #pragma unroll 8
        for (int k = 0; k < 64; ++k) {
            float xk = __shfl(xv, k);
            acc += xk * W[k * 64 + lane];
        }
        atomicAdd(&out[(long)dstn * 64 + lane], acc);
    }
}

extern "C" void kernel_launch(void* const* d_in, const int* in_sizes, int n_in,
                              void* d_out, int out_size, void* d_ws, size_t ws_size,
                              hipStream_t stream) {
    const float* x      = (const float*)d_in[0];
    const int*   ei     = (const int*)d_in[1];   // [2, E] int32
    const int*   et     = (const int*)d_in[2];   // [E]
    const float* weight = (const float*)d_in[3]; // [4, 64, 64]
    const float* root_w = (const float*)d_in[4]; // [64, 64]
    const float* root_b = (const float*)d_in[5]; // [64]
    float* out = (float*)d_out;

    const int n_nodes = in_sizes[0] / 64;
    const int n_edges = in_sizes[2];
    const size_t y_bytes = (size_t)4 * n_nodes * 64 * sizeof(float);

    const int node_blocks = (n_nodes + NT - 1) / NT;

    if (ws_size >= y_bytes) {
        float* y = (float*)d_ws;
        dim3 grid(node_blocks, 5);
        gemm5_kernel<<<grid, 256, 0, stream>>>(x, weight, root_w, root_b,
                                               out, y, n_nodes, 0);
        long total  = (long)n_edges * 16;
        int  blocks = (int)((total + 255) / 256);
        scatter_kernel<<<blocks, 256, 0, stream>>>(ei, et, y, out, n_edges, n_nodes);
    } else {
        // root part only (initializes out), then direct per-edge accumulate.
        dim3 grid(node_blocks, 1);
        gemm5_kernel<<<grid, 256, 0, stream>>>(x, weight, root_w, root_b,
                                               out, nullptr, n_nodes, 4);
        edge_direct_kernel<<<4096, 256, 0, stream>>>(x, ei, et, weight, out, n_edges);
    }
}

// Round 2
// 324.330 us; speedup vs baseline: 2.7838x; 2.7838x over previous
//
#include <hip/hip_runtime.h>

#define NT 64

// ---------------------------------------------------------------------------
// Kernel 1: five 64x64 GEMMs over all nodes.
//   m in [0,3] -> y[m] = x @ weight[m]   (to workspace)
//   m == 4     -> out  = x @ root_w + b  (initializes out)
// ---------------------------------------------------------------------------
__global__ __launch_bounds__(256) void gemm5_kernel(
    const float* __restrict__ x, const float* __restrict__ weight,
    const float* __restrict__ root_w, const float* __restrict__ root_b,
    float* __restrict__ out, float* __restrict__ y, int n_nodes, int m_off)
{
    __shared__ float xs[NT][65];
    __shared__ float ws[64][65];

    const int tid   = threadIdx.x;
    const int m     = blockIdx.y + m_off;
    const int node0 = blockIdx.x * NT;
    const float* __restrict__ W = (m < 4) ? (weight + m * 4096) : root_w;

    #pragma unroll
    for (int i = 0; i < 4; ++i) {
        int v  = tid + i * 256;
        int r  = v >> 4;
        int cq = v & 15;
        float4 w4 = reinterpret_cast<const float4*>(W)[v];
        ws[r][cq * 4 + 0] = w4.x; ws[r][cq * 4 + 1] = w4.y;
        ws[r][cq * 4 + 2] = w4.z; ws[r][cq * 4 + 3] = w4.w;
        int node = node0 + r;
        float4 x4 = (node < n_nodes)
                        ? reinterpret_cast<const float4*>(x)[node * 16 + cq]
                        : make_float4(0.f, 0.f, 0.f, 0.f);
        xs[r][cq * 4 + 0] = x4.x; xs[r][cq * 4 + 1] = x4.y;
        xs[r][cq * 4 + 2] = x4.z; xs[r][cq * 4 + 3] = x4.w;
    }
    __syncthreads();

    const int tc = (tid & 15) * 4;
    const int tr = (tid >> 4) * 4;

    float acc[4][4];
    #pragma unroll
    for (int i = 0; i < 4; ++i)
        #pragma unroll
        for (int j = 0; j < 4; ++j) acc[i][j] = 0.f;

    #pragma unroll 4
    for (int k = 0; k < 64; ++k) {
        float xv[4], wv[4];
        #pragma unroll
        for (int i = 0; i < 4; ++i) xv[i] = xs[tr + i][k];
        #pragma unroll
        for (int j = 0; j < 4; ++j) wv[j] = ws[k][tc + j];
        #pragma unroll
        for (int i = 0; i < 4; ++i)
            #pragma unroll
            for (int j = 0; j < 4; ++j) acc[i][j] += xv[i] * wv[j];
    }

    float bias[4] = {0.f, 0.f, 0.f, 0.f};
    if (m == 4) {
        #pragma unroll
        for (int j = 0; j < 4; ++j) bias[j] = root_b[tc + j];
    }
    float* __restrict__ dst = (m < 4) ? (y + (size_t)m * n_nodes * 64) : out;
    #pragma unroll
    for (int i = 0; i < 4; ++i) {
        int node = node0 + tr + i;
        if (node < n_nodes) {
            float4 o = make_float4(acc[i][0] + bias[0], acc[i][1] + bias[1],
                                   acc[i][2] + bias[2], acc[i][3] + bias[3]);
            reinterpret_cast<float4*>(dst)[node * 16 + (tc >> 2)] = o;
        }
    }
}

// --------------------------- CSR build pipeline ----------------------------
__global__ __launch_bounds__(256) void zero_kernel(int* __restrict__ p, int n)
{
    int i = blockIdx.x * 256 + threadIdx.x;
    if (i < n) p[i] = 0;
}

__global__ __launch_bounds__(256) void count_kernel(
    const int* __restrict__ ei, int* __restrict__ counts, int n_edges)
{
    int e = blockIdx.x * 256 + threadIdx.x;
    if (e < n_edges) atomicAdd(&counts[ei[n_edges + e]], 1);
}

// Single-block exclusive scan over counts[0..n) -> offsets[0..n], cursor copy.
__global__ __launch_bounds__(1024) void scan_kernel(
    const int* __restrict__ counts, int* __restrict__ offsets,
    int* __restrict__ cursor, int n)
{
    __shared__ int part[1024];
    const int tid   = threadIdx.x;
    const int chunk = (n + 1023) / 1024;
    const int lo = tid * chunk;
    const int hi = min(lo + chunk, n);

    int s = 0;
    for (int i = lo; i < hi; ++i) s += counts[i];
    part[tid] = s;
    __syncthreads();
    for (int d = 1; d < 1024; d <<= 1) {
        int v = (tid >= d) ? part[tid - d] : 0;
        __syncthreads();
        part[tid] += v;
        __syncthreads();
    }
    int run = (tid == 0) ? 0 : part[tid - 1];
    for (int i = lo; i < hi; ++i) {
        offsets[i] = run;
        cursor[i]  = run;
        run += counts[i];
    }
    if (hi == n && lo <= n) offsets[n] = run;   // last covering thread writes total
}

// Bin edges by dst: payload = src | (type << 24)  (n_nodes < 16.7M, types < 256)
__global__ __launch_bounds__(256) void fill_kernel(
    const int* __restrict__ ei, const int* __restrict__ et,
    int* __restrict__ cursor, unsigned* __restrict__ payload, int n_edges)
{
    int e = blockIdx.x * 256 + threadIdx.x;
    if (e >= n_edges) return;
    int src = ei[e];
    int dst = ei[n_edges + e];
    int t   = et[e];
    int pos = atomicAdd(&cursor[dst], 1);
    payload[pos] = (unsigned)src | ((unsigned)t << 24);
}

// ---------------------------------------------------------------------------
// Gather: 16 threads per node (each owns 4 channels). No atomics.
// ---------------------------------------------------------------------------
__global__ __launch_bounds__(256) void gather_kernel(
    const int* __restrict__ offsets, const unsigned* __restrict__ payload,
    const float* __restrict__ y, float* __restrict__ out, int n_nodes)
{
    int idx  = blockIdx.x * 256 + threadIdx.x;
    int node = idx >> 4;
    int cq   = idx & 15;
    if (node >= n_nodes) return;

    const int beg = offsets[node];
    const int end = offsets[node + 1];

    float4 acc = make_float4(0.f, 0.f, 0.f, 0.f);
    for (int p = beg; p < end; ++p) {
        unsigned pl = payload[p];
        int src = (int)(pl & 0xFFFFFFu);
        int t   = (int)(pl >> 24);
        float4 v = reinterpret_cast<const float4*>(y)[((long)t * n_nodes + src) * 16 + cq];
        acc.x += v.x; acc.y += v.y; acc.z += v.z; acc.w += v.w;
    }
    float4* o  = reinterpret_cast<float4*>(out) + (long)node * 16 + cq;
    float4 cur = *o;
    cur.x += acc.x; cur.y += acc.y; cur.z += acc.z; cur.w += acc.w;
    *o = cur;
}

// --------------------- fallback: atomic scatter (round-1) ------------------
__global__ __launch_bounds__(256) void scatter_kernel(
    const int* __restrict__ ei, const int* __restrict__ et,
    const float* __restrict__ y, float* __restrict__ out,
    int n_edges, int n_nodes)
{
    long idx = (long)blockIdx.x * blockDim.x + threadIdx.x;
    if (idx >= (long)n_edges * 16) return;
    int e  = (int)(idx >> 4);
    int cq = (int)(idx & 15);
    int src  = ei[e];
    int dstn = ei[n_edges + e];
    int t    = et[e];
    float4 v = reinterpret_cast<const float4*>(y)[((long)t * n_nodes + src) * 16 + cq];
    float* o = out + (long)dstn * 64 + cq * 4;
    atomicAdd(o + 0, v.x);
    atomicAdd(o + 1, v.y);
    atomicAdd(o + 2, v.z);
    atomicAdd(o + 3, v.w);
}

__global__ __launch_bounds__(256) void edge_direct_kernel(
    const float* __restrict__ x, const int* __restrict__ ei,
    const int* __restrict__ et, const float* __restrict__ weight,
    float* __restrict__ out, int n_edges)
{
    int gwave  = (int)((blockIdx.x * (long)blockDim.x + threadIdx.x) >> 6);
    int lane   = threadIdx.x & 63;
    int nwaves = (int)(((long)gridDim.x * blockDim.x) >> 6);
    for (int e = gwave; e < n_edges; e += nwaves) {
        int src  = ei[e];
        int dstn = ei[n_edges + e];
        int t    = et[e];
        float xv = x[src * 64 + lane];
        const float* __restrict__ W = weight + t * 4096;
        float acc = 0.f;
        #pragma unroll 8
        for (int k = 0; k < 64; ++k) {
            float xk = __shfl(xv, k);
            acc += xk * W[k * 64 + lane];
        }
        atomicAdd(&out[(long)dstn * 64 + lane], acc);
    }
}

extern "C" void kernel_launch(void* const* d_in, const int* in_sizes, int n_in,
                              void* d_out, int out_size, void* d_ws, size_t ws_size,
                              hipStream_t stream) {
    const float* x      = (const float*)d_in[0];
    const int*   ei     = (const int*)d_in[1];   // [2, E] int32
    const int*   et     = (const int*)d_in[2];   // [E]
    const float* weight = (const float*)d_in[3]; // [4, 64, 64]
    const float* root_w = (const float*)d_in[4]; // [64, 64]
    const float* root_b = (const float*)d_in[5]; // [64]
    float* out = (float*)d_out;

    const int n_nodes = in_sizes[0] / 64;
    const int n_edges = in_sizes[2];
    const size_t y_bytes   = (size_t)4 * n_nodes * 64 * sizeof(float);
    const size_t csr_bytes = y_bytes + ((size_t)3 * n_nodes + 2 + n_edges) * 4;

    const int node_blocks = (n_nodes + NT - 1) / NT;
    const int edge_blocks = (n_edges + 255) / 256;

    if (ws_size >= csr_bytes) {
        float*    y       = (float*)d_ws;
        int*      counts  = (int*)((char*)d_ws + y_bytes);
        int*      offsets = counts + n_nodes;          // n_nodes+1
        int*      cursor  = offsets + n_nodes + 1;
        unsigned* payload = (unsigned*)(cursor + n_nodes);

        zero_kernel<<<(n_nodes + 255) / 256, 256, 0, stream>>>(counts, n_nodes);
        count_kernel<<<edge_blocks, 256, 0, stream>>>(ei, counts, n_edges);
        scan_kernel<<<1, 1024, 0, stream>>>(counts, offsets, cursor, n_nodes);
        fill_kernel<<<edge_blocks, 256, 0, stream>>>(ei, et, cursor, payload, n_edges);
        dim3 grid(node_blocks, 5);
        gemm5_kernel<<<grid, 256, 0, stream>>>(x, weight, root_w, root_b,
                                               out, y, n_nodes, 0);
        int gblocks = (int)(((long)n_nodes * 16 + 255) / 256);
        gather_kernel<<<gblocks, 256, 0, stream>>>(offsets, payload, y, out, n_nodes);
    } else if (ws_size >= y_bytes) {
        float* y = (float*)d_ws;
        dim3 grid(node_blocks, 5);
        gemm5_kernel<<<grid, 256, 0, stream>>>(x, weight, root_w, root_b,
                                               out, y, n_nodes, 0);
        long total  = (long)n_edges * 16;
        int  blocks = (int)((total + 255) / 256);
        scatter_kernel<<<blocks, 256, 0, stream>>>(ei, et, y, out, n_edges, n_nodes);
    } else {
        dim3 grid(node_blocks, 1);
        gemm5_kernel<<<grid, 256, 0, stream>>>(x, weight, root_w, root_b,
                                               out, nullptr, n_nodes, 4);
        edge_direct_kernel<<<4096, 256, 0, stream>>>(x, ei, et, weight, out, n_edges);
    }
}

// Round 3
// 221.580 us; speedup vs baseline: 4.0746x; 1.4637x over previous
//
#include <hip/hip_runtime.h>

#define NT 64

// ---------------------------------------------------------------------------
// Kernel 1: five 64x64 GEMMs over all nodes.
//   m in [0,3] -> y[m] = x @ weight[m]   (to workspace)
//   m == 4     -> out  = x @ root_w + b  (initializes out)
// ---------------------------------------------------------------------------
__global__ __launch_bounds__(256) void gemm5_kernel(
    const float* __restrict__ x, const float* __restrict__ weight,
    const float* __restrict__ root_w, const float* __restrict__ root_b,
    float* __restrict__ out, float* __restrict__ y, int n_nodes, int m_off)
{
    __shared__ float xs[NT][65];
    __shared__ float ws[64][65];

    const int tid   = threadIdx.x;
    const int m     = blockIdx.y + m_off;
    const int node0 = blockIdx.x * NT;
    const float* __restrict__ W = (m < 4) ? (weight + m * 4096) : root_w;

    #pragma unroll
    for (int i = 0; i < 4; ++i) {
        int v  = tid + i * 256;
        int r  = v >> 4;
        int cq = v & 15;
        float4 w4 = reinterpret_cast<const float4*>(W)[v];
        ws[r][cq * 4 + 0] = w4.x; ws[r][cq * 4 + 1] = w4.y;
        ws[r][cq * 4 + 2] = w4.z; ws[r][cq * 4 + 3] = w4.w;
        int node = node0 + r;
        float4 x4 = (node < n_nodes)
                        ? reinterpret_cast<const float4*>(x)[node * 16 + cq]
                        : make_float4(0.f, 0.f, 0.f, 0.f);
        xs[r][cq * 4 + 0] = x4.x; xs[r][cq * 4 + 1] = x4.y;
        xs[r][cq * 4 + 2] = x4.z; xs[r][cq * 4 + 3] = x4.w;
    }
    __syncthreads();

    const int tc = (tid & 15) * 4;
    const int tr = (tid >> 4) * 4;

    float acc[4][4];
    #pragma unroll
    for (int i = 0; i < 4; ++i)
        #pragma unroll
        for (int j = 0; j < 4; ++j) acc[i][j] = 0.f;

    #pragma unroll 4
    for (int k = 0; k < 64; ++k) {
        float xv[4], wv[4];
        #pragma unroll
        for (int i = 0; i < 4; ++i) xv[i] = xs[tr + i][k];
        #pragma unroll
        for (int j = 0; j < 4; ++j) wv[j] = ws[k][tc + j];
        #pragma unroll
        for (int i = 0; i < 4; ++i)
            #pragma unroll
            for (int j = 0; j < 4; ++j) acc[i][j] += xv[i] * wv[j];
    }

    float bias[4] = {0.f, 0.f, 0.f, 0.f};
    if (m == 4) {
        #pragma unroll
        for (int j = 0; j < 4; ++j) bias[j] = root_b[tc + j];
    }
    float* __restrict__ dst = (m < 4) ? (y + (size_t)m * n_nodes * 64) : out;
    #pragma unroll
    for (int i = 0; i < 4; ++i) {
        int node = node0 + tr + i;
        if (node < n_nodes) {
            float4 o = make_float4(acc[i][0] + bias[0], acc[i][1] + bias[1],
                                   acc[i][2] + bias[2], acc[i][3] + bias[3]);
            reinterpret_cast<float4*>(dst)[node * 16 + (tc >> 2)] = o;
        }
    }
}

// --------------------------- CSR build pipeline ----------------------------
__global__ __launch_bounds__(256) void count_kernel(
    const int* __restrict__ ei, int* __restrict__ counts, int n_edges)
{
    int e = blockIdx.x * 256 + threadIdx.x;
    if (e < n_edges) atomicAdd(&counts[ei[n_edges + e]], 1);
}

// ---- multi-block exclusive scan (3 passes, 1024 elems/block) --------------
// Pass 1: per-block sums.
__global__ __launch_bounds__(256) void scan1_kernel(
    const int* __restrict__ counts, int* __restrict__ bsum, int n)
{
    __shared__ int tsum[256];
    const int tid  = threadIdx.x;
    const int base = blockIdx.x * 1024 + tid * 4;
    int s = 0;
    if (base + 3 < n) {
        int4 v = *reinterpret_cast<const int4*>(counts + base);
        s = v.x + v.y + v.z + v.w;
    } else {
        for (int i = 0; i < 4; ++i) if (base + i < n) s += counts[base + i];
    }
    tsum[tid] = s;
    __syncthreads();
    for (int d = 128; d > 0; d >>= 1) {
        if (tid < d) tsum[tid] += tsum[tid + d];
        __syncthreads();
    }
    if (tid == 0) bsum[blockIdx.x] = tsum[0];
}

// Pass 2: single-block exclusive scan of block sums (nb small), writes total
// to offsets[n].
__global__ __launch_bounds__(1024) void scan2_kernel(
    int* __restrict__ bsum, int* __restrict__ offsets, int nb, int n)
{
    __shared__ int part[1024];
    const int tid   = threadIdx.x;
    const int chunk = (nb + 1023) / 1024;
    const int lo = tid * chunk;
    const int hi = min(lo + chunk, nb);
    int s = 0;
    for (int i = lo; i < hi; ++i) s += bsum[i];
    part[tid] = s;
    __syncthreads();
    for (int d = 1; d < 1024; d <<= 1) {
        int v = (tid >= d) ? part[tid - d] : 0;
        __syncthreads();
        part[tid] += v;
        __syncthreads();
    }
    int run = (tid == 0) ? 0 : part[tid - 1];
    for (int i = lo; i < hi; ++i) {
        int c = bsum[i];
        bsum[i] = run;
        run += c;
    }
    if (tid == 1023) offsets[n] = part[1023];
}

// Pass 3: local exclusive scan + block base -> offsets & cursor.
__global__ __launch_bounds__(256) void scan3_kernel(
    const int* __restrict__ counts, const int* __restrict__ bsum,
    int* __restrict__ offsets, int* __restrict__ cursor, int n)
{
    __shared__ int tsum[256];
    const int tid  = threadIdx.x;
    const int base = blockIdx.x * 1024 + tid * 4;
    int v[4];
    #pragma unroll
    for (int i = 0; i < 4; ++i) v[i] = (base + i < n) ? counts[base + i] : 0;
    int s = v[0] + v[1] + v[2] + v[3];
    tsum[tid] = s;
    __syncthreads();
    for (int d = 1; d < 256; d <<= 1) {
        int t = (tid >= d) ? tsum[tid - d] : 0;
        __syncthreads();
        tsum[tid] += t;
        __syncthreads();
    }
    int run = bsum[blockIdx.x] + ((tid == 0) ? 0 : tsum[tid - 1]);
    #pragma unroll
    for (int i = 0; i < 4; ++i) {
        if (base + i < n) {
            offsets[base + i] = run;
            cursor[base + i]  = run;
            run += v[i];
        }
    }
}

// Bin edges by dst: payload = src | (type << 24)
__global__ __launch_bounds__(256) void fill_kernel(
    const int* __restrict__ ei, const int* __restrict__ et,
    int* __restrict__ cursor, unsigned* __restrict__ payload, int n_edges)
{
    int e = blockIdx.x * 256 + threadIdx.x;
    if (e >= n_edges) return;
    int src = ei[e];
    int dst = ei[n_edges + e];
    int t   = et[e];
    int pos = atomicAdd(&cursor[dst], 1);
    payload[pos] = (unsigned)src | ((unsigned)t << 24);
}

// ---------------------------------------------------------------------------
// Gather: 16 threads per node (each owns 4 channels). No atomics.
// ---------------------------------------------------------------------------
__global__ __launch_bounds__(256) void gather_kernel(
    const int* __restrict__ offsets, const unsigned* __restrict__ payload,
    const float* __restrict__ y, float* __restrict__ out, int n_nodes)
{
    int idx  = blockIdx.x * 256 + threadIdx.x;
    int node = idx >> 4;
    int cq   = idx & 15;
    if (node >= n_nodes) return;

    const int beg = offsets[node];
    const int end = offsets[node + 1];

    float4 acc = make_float4(0.f, 0.f, 0.f, 0.f);
    for (int p = beg; p < end; ++p) {
        unsigned pl = payload[p];
        int src = (int)(pl & 0xFFFFFFu);
        int t   = (int)(pl >> 24);
        float4 v = reinterpret_cast<const float4*>(y)[((long)t * n_nodes + src) * 16 + cq];
        acc.x += v.x; acc.y += v.y; acc.z += v.z; acc.w += v.w;
    }
    float4* o  = reinterpret_cast<float4*>(out) + (long)node * 16 + cq;
    float4 cur = *o;
    cur.x += acc.x; cur.y += acc.y; cur.z += acc.z; cur.w += acc.w;
    *o = cur;
}

// --------------------- fallback: atomic scatter (round-1) ------------------
__global__ __launch_bounds__(256) void scatter_kernel(
    const int* __restrict__ ei, const int* __restrict__ et,
    const float* __restrict__ y, float* __restrict__ out,
    int n_edges, int n_nodes)
{
    long idx = (long)blockIdx.x * blockDim.x + threadIdx.x;
    if (idx >= (long)n_edges * 16) return;
    int e  = (int)(idx >> 4);
    int cq = (int)(idx & 15);
    int src  = ei[e];
    int dstn = ei[n_edges + e];
    int t    = et[e];
    float4 v = reinterpret_cast<const float4*>(y)[((long)t * n_nodes + src) * 16 + cq];
    float* o = out + (long)dstn * 64 + cq * 4;
    atomicAdd(o + 0, v.x);
    atomicAdd(o + 1, v.y);
    atomicAdd(o + 2, v.z);
    atomicAdd(o + 3, v.w);
}

__global__ __launch_bounds__(256) void edge_direct_kernel(
    const float* __restrict__ x, const int* __restrict__ ei,
    const int* __restrict__ et, const float* __restrict__ weight,
    float* __restrict__ out, int n_edges)
{
    int gwave  = (int)((blockIdx.x * (long)blockDim.x + threadIdx.x) >> 6);
    int lane   = threadIdx.x & 63;
    int nwaves = (int)(((long)gridDim.x * blockDim.x) >> 6);
    for (int e = gwave; e < n_edges; e += nwaves) {
        int src  = ei[e];
        int dstn = ei[n_edges + e];
        int t    = et[e];
        float xv = x[src * 64 + lane];
        const float* __restrict__ W = weight + t * 4096;
        float acc = 0.f;
        #pragma unroll 8
        for (int k = 0; k < 64; ++k) {
            float xk = __shfl(xv, k);
            acc += xk * W[k * 64 + lane];
        }
        atomicAdd(&out[(long)dstn * 64 + lane], acc);
    }
}

extern "C" void kernel_launch(void* const* d_in, const int* in_sizes, int n_in,
                              void* d_out, int out_size, void* d_ws, size_t ws_size,
                              hipStream_t stream) {
    const float* x      = (const float*)d_in[0];
    const int*   ei     = (const int*)d_in[1];   // [2, E] int32
    const int*   et     = (const int*)d_in[2];   // [E]
    const float* weight = (const float*)d_in[3]; // [4, 64, 64]
    const float* root_w = (const float*)d_in[4]; // [64, 64]
    const float* root_b = (const float*)d_in[5]; // [64]
    float* out = (float*)d_out;

    const int n_nodes = in_sizes[0] / 64;
    const int n_edges = in_sizes[2];
    const int nb_scan = (n_nodes + 1023) / 1024;

    const size_t y_bytes   = (size_t)4 * n_nodes * 64 * sizeof(float);
    const size_t csr_bytes = y_bytes +
        ((size_t)3 * n_nodes + 2 + n_edges + nb_scan) * 4;

    const int node_blocks = (n_nodes + NT - 1) / NT;
    const int edge_blocks = (n_edges + 255) / 256;

    if (ws_size >= csr_bytes) {
        float*    y       = (float*)d_ws;
        int*      counts  = (int*)((char*)d_ws + y_bytes);
        int*      offsets = counts + n_nodes;          // n_nodes+1
        int*      cursor  = offsets + n_nodes + 1;
        int*      bsum    = cursor + n_nodes;          // nb_scan
        unsigned* payload = (unsigned*)(bsum + nb_scan);

        hipMemsetAsync(counts, 0, (size_t)n_nodes * 4, stream);
        count_kernel<<<edge_blocks, 256, 0, stream>>>(ei, counts, n_edges);
        scan1_kernel<<<nb_scan, 256, 0, stream>>>(counts, bsum, n_nodes);
        scan2_kernel<<<1, 1024, 0, stream>>>(bsum, offsets, nb_scan, n_nodes);
        scan3_kernel<<<nb_scan, 256, 0, stream>>>(counts, bsum, offsets, cursor, n_nodes);
        fill_kernel<<<edge_blocks, 256, 0, stream>>>(ei, et, cursor, payload, n_edges);
        dim3 grid(node_blocks, 5);
        gemm5_kernel<<<grid, 256, 0, stream>>>(x, weight, root_w, root_b,
                                               out, y, n_nodes, 0);
        int gblocks = (int)(((long)n_nodes * 16 + 255) / 256);
        gather_kernel<<<gblocks, 256, 0, stream>>>(offsets, payload, y, out, n_nodes);
    } else if (ws_size >= y_bytes) {
        float* y = (float*)d_ws;
        dim3 grid(node_blocks, 5);
        gemm5_kernel<<<grid, 256, 0, stream>>>(x, weight, root_w, root_b,
                                               out, y, n_nodes, 0);
        long total  = (long)n_edges * 16;
        int  blocks = (int)((total + 255) / 256);
        scatter_kernel<<<blocks, 256, 0, stream>>>(ei, et, y, out, n_edges, n_nodes);
    } else {
        dim3 grid(node_blocks, 1);
        gemm5_kernel<<<grid, 256, 0, stream>>>(x, weight, root_w, root_b,
                                               out, nullptr, n_nodes, 4);
        edge_direct_kernel<<<4096, 256, 0, stream>>>(x, ei, et, weight, out, n_edges);
    }
}